// Round 1
// baseline (388.627 us; speedup 1.0000x reference)
//
#include <hip/hip_runtime.h>

#define TT 32
#define NN 4096
#define BETA 0.75f

// ---------------- transpose inp [T][N] -> XT [N][T] ----------------
__global__ void k_transpose(const float* __restrict__ inp, float* __restrict__ xt) {
    int j = blockIdx.x * blockDim.x + threadIdx.x;
    if (j >= NN) return;
#pragma unroll
    for (int t = 0; t < TT; ++t) xt[j * TT + t] = inp[t * NN + j];
}

// ---------------- skinny GEMM: Cp[s][t][i] = sum_{j in Kslice s} W[i][j] * XT[j][t]
// lane = (t4 = lane>>4, k4 = lane&15); each lane: 4 rows x 8 t accumulators.
// grid = (rowblocks=256, S=4), block = 256 (4 waves x 4 rows = 16 rows/block)
__global__ __launch_bounds__(256, 4) void k_gemm(const float* __restrict__ W,
                                                 const float* __restrict__ xt,
                                                 float* __restrict__ Cp) {
    const int wave = threadIdx.x >> 6;
    const int lane = threadIdx.x & 63;
    const int k4 = lane & 15;
    const int t4 = lane >> 4;
    const int r0 = blockIdx.x * 16 + wave * 4;
    const int s = blockIdx.y;
    const int jbase = s * 1024;

    float acc[4][8];
#pragma unroll
    for (int r = 0; r < 4; ++r)
#pragma unroll
        for (int q = 0; q < 8; ++q) acc[r][q] = 0.f;

    for (int kc = 0; kc < 64; ++kc) {
        const int j = jbase + kc * 16 + k4;
        const float4 xa = *reinterpret_cast<const float4*>(xt + j * TT + t4 * 8);
        const float4 xb = *reinterpret_cast<const float4*>(xt + j * TT + t4 * 8 + 4);
#pragma unroll
        for (int r = 0; r < 4; ++r) {
            const float w = W[(r0 + r) * NN + j];
            acc[r][0] += w * xa.x;
            acc[r][1] += w * xa.y;
            acc[r][2] += w * xa.z;
            acc[r][3] += w * xa.w;
            acc[r][4] += w * xb.x;
            acc[r][5] += w * xb.y;
            acc[r][6] += w * xb.z;
            acc[r][7] += w * xb.w;
        }
    }

    // reduce across the 16 k4 lanes (stays within 16-lane groups)
#pragma unroll
    for (int r = 0; r < 4; ++r)
#pragma unroll
        for (int q = 0; q < 8; ++q) {
            float v = acc[r][q];
            v += __shfl_xor(v, 1);
            v += __shfl_xor(v, 2);
            v += __shfl_xor(v, 4);
            v += __shfl_xor(v, 8);
            acc[r][q] = v;
        }

    if (k4 == 0) {
        float* outp = Cp + (size_t)s * TT * NN;
#pragma unroll
        for (int r = 0; r < 4; ++r)
#pragma unroll
            for (int q = 0; q < 8; ++q) {
                const int t = t4 * 8 + q;
                outp[t * NN + r0 + r] = acc[r][q];
            }
    }
}

// ---------------- LIF scan for a hidden layer ----------------
// sums the 4 K-split partials, runs the t-recurrence in registers,
// writes post-reset membrane to d_out slice, spikes in both layouts.
__global__ void k_lif_hidden(const float* __restrict__ Cp,
                             float* __restrict__ memhis,    // d_out + 320 + layer*NN
                             float* __restrict__ spkT,      // [NN][TT] for next GEMM
                             float* __restrict__ spk_row) { // [TT][NN]
    const int i = blockIdx.x * blockDim.x + threadIdx.x;
    if (i >= NN) return;
    float mem = 0.f;
#pragma unroll
    for (int t = 0; t < TT; ++t) {
        const float cur = Cp[t * NN + i]
                        + Cp[1 * TT * NN + t * NN + i]
                        + Cp[2 * TT * NN + t * NN + i]
                        + Cp[3 * TT * NN + t * NN + i];
        mem = BETA * mem + cur;
        const float spk = (mem > 1.0f) ? 1.0f : 0.0f;
        mem -= spk;                    // THRESH = 1.0
        memhis[t * (3 * NN) + i] = mem;
        spkT[i * TT + t] = spk;
        spk_row[t * NN + i] = spk;
    }
}

// ---------------- output GEMV: curo[t][o] = dot(out_w[o], spk_row[t]) ----------------
__global__ void k_out_gemv(const float* __restrict__ out_w,
                           const float* __restrict__ spk_row,
                           float* __restrict__ curo) {
    const int t = blockIdx.x;
    const int tid = threadIdx.x;
    float acc[10];
#pragma unroll
    for (int o = 0; o < 10; ++o) acc[o] = 0.f;
    for (int j = tid; j < NN; j += 256) {
        const float x = spk_row[t * NN + j];
#pragma unroll
        for (int o = 0; o < 10; ++o) acc[o] += out_w[o * NN + j] * x;
    }
    __shared__ float red[10][256];
#pragma unroll
    for (int o = 0; o < 10; ++o) red[o][tid] = acc[o];
    __syncthreads();
    for (int st = 128; st > 0; st >>= 1) {
        if (tid < st) {
#pragma unroll
            for (int o = 0; o < 10; ++o) red[o][tid] += red[o][tid + st];
        }
        __syncthreads();
    }
    if (tid < 10) curo[t * 10 + tid] = red[tid][0];
}

// ---------------- output LIF scan ----------------
__global__ void k_lif_out(const float* __restrict__ curo, float* __restrict__ out_spks) {
    const int o = threadIdx.x;
    if (o >= 10) return;
    float mem = 0.f;
    for (int t = 0; t < TT; ++t) {
        mem = BETA * mem + curo[t * 10 + o];
        const float spk = (mem > 1.0f) ? 1.0f : 0.0f;
        mem -= spk;
        out_spks[t * 10 + o] = spk;
    }
}

extern "C" void kernel_launch(void* const* d_in, const int* in_sizes, int n_in,
                              void* d_out, int out_size, void* d_ws, size_t ws_size,
                              hipStream_t stream) {
    const float* inp  = (const float*)d_in[0];
    const float* fc0  = (const float*)d_in[1];
    const float* fc1  = (const float*)d_in[2];
    const float* fc2  = (const float*)d_in[3];
    const float* outw = (const float*)d_in[4];
    float* out = (float*)d_out;

    float* ws = (float*)d_ws;
    float* XT_A    = ws;                  // 131072 floats  [NN][TT]
    float* XT_B    = ws + 131072;         // 131072
    float* spk_row = ws + 262144;         // 131072  [TT][NN]
    float* curo    = ws + 393216;         // 320
    float* Cp      = ws + 393536;         // 4 * 32 * 4096 = 524288 partials
    // total ws use: 917824 floats ~= 3.5 MiB

    float* memh0 = out + 320;             // mem_his[t][0][i] at 320 + t*3*NN + 0*NN + i
    float* memh1 = out + 320 + NN;
    float* memh2 = out + 320 + 2 * NN;

    k_transpose<<<16, 256, 0, stream>>>(inp, XT_A);

    k_gemm<<<dim3(256, 4), 256, 0, stream>>>(fc0, XT_A, Cp);
    k_lif_hidden<<<16, 256, 0, stream>>>(Cp, memh0, XT_B, spk_row);

    k_gemm<<<dim3(256, 4), 256, 0, stream>>>(fc1, XT_B, Cp);
    k_lif_hidden<<<16, 256, 0, stream>>>(Cp, memh1, XT_A, spk_row);

    k_gemm<<<dim3(256, 4), 256, 0, stream>>>(fc2, XT_A, Cp);
    k_lif_hidden<<<16, 256, 0, stream>>>(Cp, memh2, XT_B, spk_row);

    k_out_gemv<<<32, 256, 0, stream>>>(outw, spk_row, curo);
    k_lif_out<<<1, 64, 0, stream>>>(curo, out);
}